// Round 3
// baseline (245.120 us; speedup 1.0000x reference)
//
#include <hip/hip_runtime.h>
#include <hip/hip_fp16.h>

typedef _Float16 f16;
typedef _Float16 f16x4 __attribute__((ext_vector_type(4)));
typedef _Float16 f16x8 __attribute__((ext_vector_type(8)));
typedef float f32x4 __attribute__((ext_vector_type(4)));

#define B_ 256
#define N_ 2048
#define D_ 256
#define M_TOTAL (B_ * N_)      // 524288
#define BM 64
#define NTILES (M_TOTAL / BM)  // 8192
#define GRID_MAIN 256
#define TPW (NTILES / GRID_MAIN)  // 32 tiles per block == one batch

// ---------------------------------------------------------------------------
// prep_w: W[0][d][k] (k<256, feature half) -> fp16 hi/lo planes in MFMA
// B-fragment order: plane[p][ctg][ks][lane][j].
//   ctg = d>>4, lane = (d&15) | (((k>>3)&3)<<4), ks = k>>5, j = k&7
// ---------------------------------------------------------------------------
__global__ void prep_w(const float* __restrict__ W, f16* __restrict__ wbuf) {
    int idx = blockIdx.x * 256 + threadIdx.x;   // 65536 total
    int d = idx >> 8, k = idx & 255;
    float w = W[d * 512 + k];
    f16 hi = (f16)w;
    f16 lo = (f16)(w - (float)hi);
    int ctg  = d >> 4;
    int lane = (d & 15) | (((k >> 3) & 3) << 4);
    int ks   = k >> 5;
    int j    = k & 7;
    int off  = ((ctg * 8 + ks) * 64 + lane) * 8 + j;
    wbuf[off]         = hi;
    wbuf[65536 + off] = lo;
}

// ---------------------------------------------------------------------------
// prep_c: c[b][d] = sum_e W[0][d][256+e] * h[b][e]   (fp32 exact, tiny)
// ---------------------------------------------------------------------------
__global__ void prep_c(const float* __restrict__ W, const float* __restrict__ h,
                       float* __restrict__ c) {
    __shared__ float hs[256];
    int b = blockIdx.x, d = threadIdx.x;
    hs[d] = h[b * 256 + d];
    __syncthreads();
    const float4* w4 = (const float4*)(W + d * 512 + 256);
    const float4* h4 = (const float4*)hs;
    float acc = 0.f;
#pragma unroll 8
    for (int e = 0; e < 64; ++e) {
        float4 a = w4[e], bb = h4[e];
        acc += a.x * bb.x + a.y * bb.y + a.z * bb.z + a.w * bb.w;
    }
    c[b * 256 + d] = acc;
}

// ---------------------------------------------------------------------------
// Staging: full 64x256 tile (64 KB f32 -> 32 KB f16) per step.
// Thread (srow = tid>>6, scol = tid&63): load i reads row i*8+srow, 16 B at
// scol*16 -> each wave reads one full 1 KB row per instruction (coalesced).
// LDS write: f16x4 at byte (row*512 + scol*8) ^ ((row&7)<<4)  (conflict-free).
// ---------------------------------------------------------------------------
__device__ __forceinline__ void write_tile(char* dst, const float4* st,
                                           int srow, int scol) {
#pragma unroll
    for (int i = 0; i < 8; ++i) {
        int row = i * 8 + srow;
        f16x4 hv;
        hv[0] = (f16)st[i].x; hv[1] = (f16)st[i].y;
        hv[2] = (f16)st[i].z; hv[3] = (f16)st[i].w;
        int byte = (row * 512 + scol * 8) ^ ((row & 7) << 4);
        *(f16x4*)(dst + byte) = hv;
    }
}

// ---------------------------------------------------------------------------
// main_gemm: 2-pass split precision (f_hi*W_hi + f_hi*W_lo). Full-K tiles,
// double-buffered LDS (2x32 KB), 3 barriers/tile. Block b owns batch b.
// 8 waves x 32 d-cols; W frags (hi+lo) resident in registers.
// ---------------------------------------------------------------------------
__global__ __launch_bounds__(512, 2)
void main_gemm(const float* __restrict__ feat, const f16* __restrict__ wbuf,
               const float* __restrict__ cb, const float* __restrict__ vvec,
               float* __restrict__ scores) {
    __shared__ __align__(16) char lds[65536];   // 2 x 32 KB A-tile buffers

    const int tid = threadIdx.x;
    const int w = tid >> 6;       // wave 0..7
    const int l = tid & 63;
    const int wcol0 = w * 32;
    const int g = l >> 4;
    const int b = blockIdx.x;     // == batch index

    // ---- W fragments (hi+lo planes) into registers: 128 VGPRs ----
    f16x8 wf[2][2][8];
    {
        const f16x8* wp = (const f16x8*)wbuf;
#pragma unroll
        for (int p = 0; p < 2; ++p)
#pragma unroll
            for (int ct = 0; ct < 2; ++ct) {
                int ctg = (wcol0 >> 4) + ct;
#pragma unroll
                for (int ks = 0; ks < 8; ++ks)
                    wf[p][ct][ks] = wp[p * 8192 + (ctg * 8 + ks) * 64 + l];
            }
    }
    const float vv0 = vvec[wcol0 + (l & 15)];
    const float vv1 = vvec[wcol0 + 16 + (l & 15)];
    const float c0 = cb[b * 256 + wcol0 + (l & 15)];
    const float c1 = cb[b * 256 + wcol0 + 16 + (l & 15)];

    const int srow = tid >> 6;    // 0..7
    const int scol = tid & 63;    // 0..63

    // per-thread feature pointer; advances 16384 floats (one tile) per step
    const float* fptr = feat + (size_t)b * (TPW * BM * 256) + srow * 256 + scol * 4;

    float4 st[8];
    // ---- prologue: stage tile 0 into buf0 ----
#pragma unroll
    for (int i = 0; i < 8; ++i) st[i] = *(const float4*)(fptr + i * 2048);
    write_tile(lds, st, srow, scol);
    fptr += 16384;

    for (int t = 0; t < TPW; ++t) {
        char* P = lds + (t & 1) * 32768;
        char* Q = lds + ((t + 1) & 1) * 32768;
        __syncthreads();          // barrier1: P fully staged
        const bool more = (t < TPW - 1);
        if (more) {
#pragma unroll
            for (int i = 0; i < 8; ++i) st[i] = *(const float4*)(fptr + i * 2048);
        }

        f32x4 acc[4][2] = {};
#pragma unroll
        for (int ksg = 0; ksg < 8; ++ksg) {
#pragma unroll
            for (int rt = 0; rt < 4; ++rt) {
                int row = rt * 16 + (l & 15);
                int byte = (row * 512 + ksg * 64 + g * 16) ^ ((row & 7) << 4);
                f16x8 ah = *(const f16x8*)(P + byte);
                acc[rt][0] = __builtin_amdgcn_mfma_f32_16x16x32_f16(ah, wf[0][0][ksg], acc[rt][0], 0, 0, 0);
                acc[rt][1] = __builtin_amdgcn_mfma_f32_16x16x32_f16(ah, wf[0][1][ksg], acc[rt][1], 0, 0, 0);
                acc[rt][0] = __builtin_amdgcn_mfma_f32_16x16x32_f16(ah, wf[1][0][ksg], acc[rt][0], 0, 0, 0);
                acc[rt][1] = __builtin_amdgcn_mfma_f32_16x16x32_f16(ah, wf[1][1][ksg], acc[rt][1], 0, 0, 0);
            }
        }

        // ---- epilogue compute (registers only): +c, tanh, *v, 16-lane reduce
        float sv[4][4];
#pragma unroll
        for (int rt = 0; rt < 4; ++rt) {
#pragma unroll
            for (int r = 0; r < 4; ++r) {
                float x0 = acc[rt][0][r] + c0;
                float x1 = acc[rt][1][r] + c1;
                float e0 = __expf(2.f * x0);
                float e1 = __expf(2.f * x1);
                float t0 = 1.f - __fdividef(2.f, e0 + 1.f);
                float t1 = 1.f - __fdividef(2.f, e1 + 1.f);
                sv[rt][r] = vv0 * t0 + vv1 * t1;
            }
#pragma unroll
            for (int m = 1; m < 16; m <<= 1) {
                sv[rt][0] += __shfl_xor(sv[rt][0], m, 64);
                sv[rt][1] += __shfl_xor(sv[rt][1], m, 64);
                sv[rt][2] += __shfl_xor(sv[rt][2], m, 64);
                sv[rt][3] += __shfl_xor(sv[rt][3], m, 64);
            }
        }
        __syncthreads();          // barrier2: all MFMA reads of P complete
        float* rbuf = (float*)P;  // rbuf aliases the just-consumed buffer
#pragma unroll
        for (int rt = 0; rt < 4; ++rt) {
            if ((l & 15) == 0) {
                int r0 = rt * 16 + g * 4;
                rbuf[(r0 + 0) * 9 + w] = sv[rt][0];
                rbuf[(r0 + 1) * 9 + w] = sv[rt][1];
                rbuf[(r0 + 2) * 9 + w] = sv[rt][2];
                rbuf[(r0 + 3) * 9 + w] = sv[rt][3];
            }
        }
        __syncthreads();          // barrier3: rbuf ready
        if (tid < 64) {
            float s = 0.f;
#pragma unroll
            for (int ww = 0; ww < 8; ++ww) s += rbuf[tid * 9 + ww];
            scores[((size_t)b * TPW + t) * BM + tid] = s;
        }
        if (more) {
            write_tile(Q, st, srow, scol);  // compiler inserts vmcnt for st
            fptr += 16384;
        }
    }
}

// ---------------------------------------------------------------------------
// softmax over n (2048) per b; out[b*2048+n]
// ---------------------------------------------------------------------------
__global__ void softmax_k(const float* __restrict__ scores, float* __restrict__ out) {
    __shared__ float red[16];
    int b = blockIdx.x, tid = threadIdx.x;  // 256 threads
    const float4* s4 = (const float4*)(scores + b * 2048);
    float4 x0 = s4[tid], x1 = s4[tid + 256];
    float m = fmaxf(fmaxf(fmaxf(x0.x, x0.y), fmaxf(x0.z, x0.w)),
                    fmaxf(fmaxf(x1.x, x1.y), fmaxf(x1.z, x1.w)));
#pragma unroll
    for (int d = 1; d < 64; d <<= 1) m = fmaxf(m, __shfl_xor(m, d, 64));
    if ((tid & 63) == 0) red[tid >> 6] = m;
    __syncthreads();
    m = fmaxf(fmaxf(red[0], red[1]), fmaxf(red[2], red[3]));
    float e0 = __expf(x0.x - m), e1 = __expf(x0.y - m), e2 = __expf(x0.z - m), e3 = __expf(x0.w - m);
    float e4 = __expf(x1.x - m), e5 = __expf(x1.y - m), e6 = __expf(x1.z - m), e7 = __expf(x1.w - m);
    float sum = ((e0 + e1) + (e2 + e3)) + ((e4 + e5) + (e6 + e7));
#pragma unroll
    for (int d = 1; d < 64; d <<= 1) sum += __shfl_xor(sum, d, 64);
    if ((tid & 63) == 0) red[8 + (tid >> 6)] = sum;
    __syncthreads();
    sum = (red[8] + red[9]) + (red[10] + red[11]);
    float inv = __fdividef(1.f, sum);
    float4 o0 = {e0 * inv, e1 * inv, e2 * inv, e3 * inv};
    float4 o1 = {e4 * inv, e5 * inv, e6 * inv, e7 * inv};
    float4* o4 = (float4*)(out + b * 2048);
    o4[tid] = o0;
    o4[tid + 256] = o1;
}

// ---------------------------------------------------------------------------
extern "C" void kernel_launch(void* const* d_in, const int* in_sizes, int n_in,
                              void* d_out, int out_size, void* d_ws, size_t ws_size,
                              hipStream_t stream) {
    const float* feat = (const float*)d_in[0];   // [256,2048,256]
    const float* h    = (const float*)d_in[1];   // [256,256]
    const float* v    = (const float*)d_in[2];   // [256]
    const float* W    = (const float*)d_in[3];   // [256,512]
    float* out = (float*)d_out;                  // [256,1,2048]

    f16*   wbuf   = (f16*)d_ws;                          // 262144 B
    float* cbuf   = (float*)((char*)d_ws + 262144);      // 262144 B
    float* scores = (float*)((char*)d_ws + 524288);      // 2 MiB

    prep_w<<<256, 256, 0, stream>>>(W, wbuf);
    prep_c<<<256, 256, 0, stream>>>(W, h, cbuf);
    main_gemm<<<GRID_MAIN, 512, 0, stream>>>(feat, wbuf, cbuf, v, scores);
    softmax_k<<<256, 256, 0, stream>>>(scores, out);
}